// Round 1
// baseline (2890.362 us; speedup 1.0000x reference)
//
#include <hip/hip_runtime.h>

// ---------------------------------------------------------------------------
// UNet DeltaNet forward, MI355X/gfx950 — round 4.
// fp32 in/out; q/k/v/o intermediates bf16 (fp32 accumulation).
// Shapes: B=8, C=768, L=4096, n_heads=12, D=64, CHUNK=64, BH=96.
//
// Round-4 restructure: the old k_fused (96 blocks, fp32 VALU, serial solve)
// is split into:
//  5a) k_pre : grid (64 chunks x 96 bh) = 6144 blocks. Per chunk:
//              As = strict(beta_i*KK^T); solve (I+As)X=[bK|bV] (register-
//              resident unrolled fwd-substitution, 128 parallel cols);
//              write Kw = T^-1 bK, Vw = T^-1 bV (over v), Aqk = tril(QK^T),
//              and K^T in place over k.  All chunk-parallel.
//  5b) k_seq : grid (96 bh). Serial 64-chunk scan, MFMA 16x16x32 bf16:
//              U = Vw - Kw*S ; O = Q*S + Aqk*U ; S += K^T*U.
//              S fp32 + bf16 operand copy in LDS (XOR-swizzled i^((e&7)<<3)
//              so ds_read_b128 B-frags are ~2-way-conflict free).
// Workspace: q,k,v,o,Kw,Aqk bf16 (6 x 50.33 MB) + beta fp32 = 303.6 MB
// (< round-1's known-good 308 MB).
// ---------------------------------------------------------------------------

#define B_  8
#define C_  768
#define L_  4096
#define NH_ 12
#define D_  64
#define NC_ 64
#define BH_ 96

typedef unsigned short ushort_t;
typedef float f32x4 __attribute__((ext_vector_type(4)));
typedef unsigned short u16x4 __attribute__((ext_vector_type(4)));
typedef unsigned short u16x8 __attribute__((ext_vector_type(8)));
using short8 = __attribute__((ext_vector_type(8))) short;

__device__ __forceinline__ float b2f(ushort_t u) {
  union { unsigned u; float f; } x; x.u = ((unsigned)u) << 16; return x.f;
}
__device__ __forceinline__ ushort_t f2b(float f) {
  union { float f; unsigned u; } x; x.f = f;
  unsigned r = (x.u + 0x7FFFu + ((x.u >> 16) & 1u)) >> 16;
  return (ushort_t)r;
}
__device__ __forceinline__ f32x4 mfma16(short8 a, short8 b, f32x4 c) {
  return __builtin_amdgcn_mfma_f32_16x16x32_bf16(a, b, c, 0, 0, 0);
}

// XOR-swizzled [e][i] index for 64x64 tiles: bijective within each column's
// 8-groups; keeps u16x4/short8/f32x4 accesses aligned & contiguous.
#define SWZ(e, i) (((e) * 64) + ((i) ^ (((e) & 7) << 3)))

// ---------------------------------------------------------------------------
// beta = sigmoid(x^T @ Wb); grid (L/256, B), 256 thr.
__global__ __launch_bounds__(256) void k_beta(
    const float* __restrict__ x, const float* __restrict__ Wb,
    float* __restrict__ beta) {
  __shared__ float wb[C_ * NH_];   // 36 KB
  int tid = threadIdx.x;
  for (int i = tid; i < C_ * NH_; i += 256) wb[i] = Wb[i];
  __syncthreads();
  int b = blockIdx.y;
  int l = blockIdx.x * 256 + tid;
  f32x4 a0 = {0.f, 0.f, 0.f, 0.f}, a1 = a0, a2 = a0;
  const float* xb = x + (size_t)b * C_ * L_ + l;
  for (int c = 0; c < C_; ++c) {
    float xv = xb[(size_t)c * L_];
    const f32x4* wr = (const f32x4*)&wb[c * NH_];
    a0 += xv * wr[0]; a1 += xv * wr[1]; a2 += xv * wr[2];
  }
  float* bp = beta + (size_t)b * NH_ * L_ + l;
  #pragma unroll
  for (int h = 0; h < 4; ++h) {
    bp[(size_t)h * L_]       = 1.f / (1.f + expf(-a0[h]));
    bp[(size_t)(h + 4) * L_] = 1.f / (1.f + expf(-a1[h]));
    bp[(size_t)(h + 8) * L_] = 1.f / (1.f + expf(-a2[h]));
  }
}

// ---------------------------------------------------------------------------
// Projection GEMM: out[b][h][l][d] = epi( sum_c x[b][c][l] * W[c][h*64+d] )
// 128x64 C-tile, thread = 8x4. grid (L/128, NH, B), 256 thr. Output bf16.
__global__ __launch_bounds__(256) void k_proj(
    const float* __restrict__ x, const float* __restrict__ W,
    ushort_t* __restrict__ outp, int norm) {
  __shared__ float As[32 * 128];  // 16 KB  As[kk][row]
  __shared__ float Bs[32 * 64];   //  8 KB  Bs[kk][col]
  int tid = threadIdx.x;
  int b = blockIdx.z, h = blockIdx.y;
  int l0 = blockIdx.x * 128;
  int ti = tid >> 4, tj = tid & 15;
  float acc[8][4];
  #pragma unroll
  for (int r = 0; r < 8; ++r)
    #pragma unroll
    for (int s = 0; s < 4; ++s) acc[r][s] = 0.f;
  const float* xb = x + (size_t)b * C_ * L_ + l0;
  const float* wb = W + h * 64;
  for (int kb = 0; kb < C_; kb += 32) {
    #pragma unroll
    for (int it = 0; it < 4; ++it) {
      int e = tid + it * 256;          // 1024 f32x4
      int kk = e >> 5, lq = e & 31;
      *(f32x4*)&As[kk * 128 + lq * 4] =
          *(const f32x4*)(xb + (size_t)(kb + kk) * L_ + lq * 4);
    }
    #pragma unroll
    for (int it = 0; it < 2; ++it) {
      int e = tid + it * 256;          // 512 f32x4
      int kk = e >> 4, nq = e & 15;
      *(f32x4*)&Bs[kk * 64 + nq * 4] =
          *(const f32x4*)(wb + (size_t)(kb + kk) * C_ + nq * 4);
    }
    __syncthreads();
    #pragma unroll 8
    for (int kk = 0; kk < 32; ++kk) {
      f32x4 a0 = *(const f32x4*)&As[kk * 128 + ti * 8];
      f32x4 a1 = *(const f32x4*)&As[kk * 128 + ti * 8 + 4];
      f32x4 bv = *(const f32x4*)&Bs[kk * 64 + tj * 4];
      #pragma unroll
      for (int r = 0; r < 4; ++r)
        #pragma unroll
        for (int s = 0; s < 4; ++s) {
          acc[r][s]     += a0[r] * bv[s];
          acc[r + 4][s] += a1[r] * bv[s];
        }
    }
    __syncthreads();
  }
  #pragma unroll
  for (int r = 0; r < 8; ++r)
    #pragma unroll
    for (int s = 0; s < 4; ++s) {
      float xv = acc[r][s];
      acc[r][s] = xv / (1.f + expf(-xv));
    }
  if (norm) {
    #pragma unroll
    for (int r = 0; r < 8; ++r) {
      float ss = acc[r][0]*acc[r][0] + acc[r][1]*acc[r][1]
               + acc[r][2]*acc[r][2] + acc[r][3]*acc[r][3];
      ss += __shfl_xor(ss, 1); ss += __shfl_xor(ss, 2);
      ss += __shfl_xor(ss, 4); ss += __shfl_xor(ss, 8);
      float rs = rsqrtf(ss + 1e-6f);
      #pragma unroll
      for (int s = 0; s < 4; ++s) acc[r][s] *= rs;
    }
  }
  ushort_t* ob = outp + (((size_t)b * NH_ + h) * L_ + l0 + ti * 8) * 64 + tj * 4;
  #pragma unroll
  for (int r = 0; r < 8; ++r) {
    u16x4 pv = {f2b(acc[r][0]), f2b(acc[r][1]), f2b(acc[r][2]), f2b(acc[r][3])};
    *(u16x4*)(ob + (size_t)r * 64) = pv;
  }
}

// ---------------------------------------------------------------------------
// k_pre: per (chunk, bh): Kw/Vw = T^-1 [bK|bV], Aqk = tril(QK^T), K -> K^T.
// grid (NC, BH), 256 thr, ~49 KB LDS (3 blocks/CU).
__global__ __launch_bounds__(256) void k_pre(
    const ushort_t* __restrict__ qg, ushort_t* __restrict__ kg,
    ushort_t* __restrict__ vg, const float* __restrict__ betag,
    ushort_t* __restrict__ kwg, ushort_t* __restrict__ aqg) {
  __shared__ float As[64 * 64];   // 16 KB  strict beta_i*KK^T (0 on/above diag)
  __shared__ float XK[64 * 64];   // 16 KB  beta*K -> Kw
  __shared__ float B2[64 * 68];   // 17 KB  Kc fp32 (padded), later XV (stride 64)
  float* Kc = B2;
  float* XV = B2;                 // alias: Kc dead before XV written
  int tid = threadIdx.x;
  int nc = blockIdx.x, bh = blockIdx.y;
  const size_t cb = ((size_t)bh * 64 + nc) * 4096;
  const float* bb = betag + (size_t)bh * L_ + nc * 64;
  int ti = tid >> 4, tj = tid & 15;
  // ---- p1: stage K chunk bf16 -> fp32 Kc (stride 68)
  #pragma unroll
  for (int it = 0; it < 2; ++it) {
    int e = tid + it * 256;            // 512 units of 8
    int i = e >> 3, c0 = (e & 7) * 8;
    u16x8 kv8 = *(const u16x8*)(kg + cb + (size_t)i * 64 + c0);
    f32x4 lo = {b2f(kv8[0]), b2f(kv8[1]), b2f(kv8[2]), b2f(kv8[3])};
    f32x4 hi = {b2f(kv8[4]), b2f(kv8[5]), b2f(kv8[6]), b2f(kv8[7])};
    *(f32x4*)&Kc[i * 68 + c0]     = lo;
    *(f32x4*)&Kc[i * 68 + c0 + 4] = hi;
  }
  __syncthreads();
  // ---- p2: As = strict(beta_i*KK^T); XK = beta*K; Aqk; K^T in place.
  {
    float kk[4][4];
    #pragma unroll
    for (int r = 0; r < 4; ++r)
      #pragma unroll
      for (int s = 0; s < 4; ++s) kk[r][s] = 0.f;
    for (int d = 0; d < 64; d += 4) {
      f32x4 ka[4], kj[4];
      #pragma unroll
      for (int r = 0; r < 4; ++r) ka[r] = *(const f32x4*)&Kc[(ti*4+r)*68 + d];
      #pragma unroll
      for (int s = 0; s < 4; ++s) kj[s] = *(const f32x4*)&Kc[(tj*4+s)*68 + d];
      #pragma unroll
      for (int r = 0; r < 4; ++r)
        #pragma unroll
        for (int s = 0; s < 4; ++s)
          #pragma unroll
          for (int q = 0; q < 4; ++q) kk[r][s] += ka[r][q] * kj[s][q];
    }
    #pragma unroll
    for (int r = 0; r < 4; ++r) {
      int i = ti * 4 + r;
      float bi = bb[i];
      #pragma unroll
      for (int s = 0; s < 4; ++s) {
        int j = tj * 4 + s;
        As[i * 64 + j] = (j < i) ? bi * kk[r][s] : 0.f;
      }
    }
  }
  #pragma unroll
  for (int it = 0; it < 2; ++it) {
    int e = tid + it * 256;
    int i = e >> 3, c0 = (e & 7) * 8;
    float bi = bb[i];
    f32x4 lo = *(const f32x4*)&Kc[i * 68 + c0];
    f32x4 hi = *(const f32x4*)&Kc[i * 68 + c0 + 4];
    *(f32x4*)&XK[i * 64 + c0]     = bi * lo;
    *(f32x4*)&XK[i * 64 + c0 + 4] = bi * hi;
  }
  {  // Aqk = tril(QK^T) incl diag -> global bf16
    float qk[4][4];
    #pragma unroll
    for (int r = 0; r < 4; ++r)
      #pragma unroll
      for (int s = 0; s < 4; ++s) qk[r][s] = 0.f;
    for (int d = 0; d < 64; d += 4) {
      f32x4 qa[4], kj[4];
      #pragma unroll
      for (int r = 0; r < 4; ++r) {
        u16x4 qv4 = *(const u16x4*)(qg + cb + (size_t)(ti*4+r) * 64 + d);
        f32x4 qv = {b2f(qv4[0]), b2f(qv4[1]), b2f(qv4[2]), b2f(qv4[3])};
        qa[r] = qv;
      }
      #pragma unroll
      for (int s = 0; s < 4; ++s) kj[s] = *(const f32x4*)&Kc[(tj*4+s)*68 + d];
      #pragma unroll
      for (int r = 0; r < 4; ++r)
        #pragma unroll
        for (int s = 0; s < 4; ++s)
          #pragma unroll
          for (int q = 0; q < 4; ++q) qk[r][s] += qa[r][q] * kj[s][q];
    }
    #pragma unroll
    for (int r = 0; r < 4; ++r) {
      int i = ti * 4 + r;
      u16x4 st;
      #pragma unroll
      for (int s = 0; s < 4; ++s) {
        int j = tj * 4 + s;
        st[s] = (j <= i) ? f2b(qk[r][s]) : (ushort_t)0;
      }
      *(u16x4*)(aqg + cb + (size_t)i * 64 + tj * 4) = st;
    }
  }
  // K^T in place over k (k chunk fully consumed in p1; block-local)
  #pragma unroll
  for (int it = 0; it < 16; ++it) {
    int u2 = tid + it * 256;     // 4096
    int d = u2 >> 6, i = u2 & 63;
    kg[cb + (size_t)d * 64 + i] = f2b(Kc[i * 68 + d]);
  }
  __syncthreads();
  // ---- p3: XV = beta*V (clobbers Kc alias — Kc dead now)
  #pragma unroll
  for (int it = 0; it < 2; ++it) {
    int e = tid + it * 256;
    int i = e >> 3, c0 = (e & 7) * 8;
    u16x8 vv8 = *(const u16x8*)(vg + cb + (size_t)i * 64 + c0);
    float bi = bb[i];
    #pragma unroll
    for (int s = 0; s < 8; ++s) XV[i * 64 + c0 + s] = bi * b2f(vv8[s]);
  }
  __syncthreads();
  // ---- solve (I+As) X = X : unit-lower fwd substitution, 128 parallel cols,
  // column register-resident (all indices static under full unroll).
  if (tid < 128) {
    int col = tid;
    float* Xc = (col < 64) ? (XK + col) : (XV + (col - 64));
    f32x4 xr[16];
    #pragma unroll
    for (int ib = 0; ib < 16; ++ib)
      #pragma unroll
      for (int q = 0; q < 4; ++q) xr[ib][q] = Xc[(ib * 4 + q) * 64];
    #pragma unroll
    for (int i = 1; i < 64; ++i) {
      float xi = xr[i >> 2][i & 3];
      #pragma unroll
      for (int ib = 0; ib * 4 < i; ++ib) {   // As==0 at/above diag handles tail
        f32x4 a4 = *(const f32x4*)&As[i * 64 + ib * 4];
        xi -= a4[0]*xr[ib][0] + a4[1]*xr[ib][1]
            + a4[2]*xr[ib][2] + a4[3]*xr[ib][3];
      }
      xr[i >> 2][i & 3] = xi;
    }
    #pragma unroll
    for (int ib = 0; ib < 16; ++ib)
      #pragma unroll
      for (int q = 0; q < 4; ++q) Xc[(ib * 4 + q) * 64] = xr[ib][q];
  }
  __syncthreads();
  // ---- write Kw (row-major bf16) and Vw (row-major bf16, over v)
  #pragma unroll
  for (int it = 0; it < 4; ++it) {
    int u = tid + it * 256;       // 1024 units
    int i = u >> 4, d0 = (u & 15) * 4;
    f32x4 xk = *(const f32x4*)&XK[i * 64 + d0];
    f32x4 xv = *(const f32x4*)&XV[i * 64 + d0];
    u16x4 pk = {f2b(xk[0]), f2b(xk[1]), f2b(xk[2]), f2b(xk[3])};
    u16x4 pv = {f2b(xv[0]), f2b(xv[1]), f2b(xv[2]), f2b(xv[3])};
    *(u16x4*)(kwg + cb + (size_t)i * 64 + d0) = pk;
    *(u16x4*)(vg  + cb + (size_t)i * 64 + d0) = pv;
  }
}

// ---------------------------------------------------------------------------
// k_seq: serial 64-chunk scan per (b,h), MFMA 16x16x32 bf16.
// U = Vw - Kw*S ; O = Q*S + Aqk*U ; S += K^T*U.  S fp32 (ST) + bf16 copy
// (SbT), both stored [e][d] with XOR swizzle.  grid (BH), 256 thr, 32 KB LDS.
__global__ __launch_bounds__(256) void k_seq(
    const ushort_t* __restrict__ qg,  const ushort_t* __restrict__ ktg,
    const ushort_t* __restrict__ kwg, const ushort_t* __restrict__ vwg,
    const ushort_t* __restrict__ aqg, ushort_t* __restrict__ og) {
  __shared__ float    STs[64 * 64];   // 16 KB  S^T fp32 [e][d] (swizzled)
  __shared__ ushort_t SbT[64 * 64];   //  8 KB  S^T bf16
  __shared__ ushort_t UT [64 * 64];   //  8 KB  U^T bf16 [e][i]
  int tid = threadIdx.x, bh = blockIdx.x;
  int w  = tid >> 6, l = tid & 63;
  int lr = l & 15, lk = l >> 4;
  int mrow = w * 16 + lr;             // A-frag row (i for M1/M2, d for M3)
  int r0   = w * 16 + lk * 4;         // C/D-frag row base
  for (int i = tid; i < 4096; i += 256) { STs[i] = 0.f; SbT[i] = 0; }
  int b = bh / NH_, h = bh % NH_;
  ushort_t* ob = og + (size_t)b * L_ * C_ + h * 64;
  __syncthreads();
  for (int nc = 0; nc < NC_; ++nc) {
    const size_t cb = ((size_t)bh * 64 + nc) * 4096;
    const ushort_t* Kw = kwg + cb;
    const ushort_t* Qc = qg  + cb;
    const ushort_t* Aq = aqg + cb;
    const ushort_t* KT = ktg + cb;
    const ushort_t* Vw = vwg + cb;
    // hoist all global loads for this chunk (one latency hit per chunk)
    short8 a_kw0 = *(const short8*)(Kw + mrow * 64 + lk * 8);
    short8 a_kw1 = *(const short8*)(Kw + mrow * 64 + 32 + lk * 8);
    short8 a_q0  = *(const short8*)(Qc + mrow * 64 + lk * 8);
    short8 a_q1  = *(const short8*)(Qc + mrow * 64 + 32 + lk * 8);
    short8 a_aq0 = *(const short8*)(Aq + mrow * 64 + lk * 8);
    short8 a_aq1 = *(const short8*)(Aq + mrow * 64 + 32 + lk * 8);
    short8 a_kt0 = *(const short8*)(KT + mrow * 64 + lk * 8);
    short8 a_kt1 = *(const short8*)(KT + mrow * 64 + 32 + lk * 8);
    float vwv[4][4];
    #pragma unroll
    for (int t = 0; t < 4; ++t)
      #pragma unroll
      for (int r = 0; r < 4; ++r)
        vwv[t][r] = b2f(Vw[(size_t)(r0 + r) * 64 + t * 16 + lr]);
    // ---- M1: U = Vw - Kw @ S
    #pragma unroll
    for (int t = 0; t < 4; ++t) {
      int e = t * 16 + lr;
      f32x4 acc = {0.f, 0.f, 0.f, 0.f};
      short8 b0 = *(const short8*)(SbT + SWZ(e, lk * 8));
      short8 b1 = *(const short8*)(SbT + SWZ(e, 32 + lk * 8));
      acc = mfma16(a_kw0, b0, acc);
      acc = mfma16(a_kw1, b1, acc);
      u16x4 uo;
      #pragma unroll
      for (int r = 0; r < 4; ++r) uo[r] = f2b(vwv[t][r] - acc[r]);
      *(u16x4*)(UT + SWZ(e, r0)) = uo;
    }
    __syncthreads();
    // ---- M2: O = Q @ S + Aqk @ U  -> global bf16
    #pragma unroll
    for (int t = 0; t < 4; ++t) {
      int e = t * 16 + lr;
      f32x4 acc = {0.f, 0.f, 0.f, 0.f};
      short8 s0 = *(const short8*)(SbT + SWZ(e, lk * 8));
      short8 s1 = *(const short8*)(SbT + SWZ(e, 32 + lk * 8));
      short8 u0 = *(const short8*)(UT  + SWZ(e, lk * 8));
      short8 u1 = *(const short8*)(UT  + SWZ(e, 32 + lk * 8));
      acc = mfma16(a_q0,  s0, acc);
      acc = mfma16(a_q1,  s1, acc);
      acc = mfma16(a_aq0, u0, acc);
      acc = mfma16(a_aq1, u1, acc);
      #pragma unroll
      for (int r = 0; r < 4; ++r)
        ob[(size_t)(nc * 64 + r0 + r) * C_ + e] = f2b(acc[r]);
    }
    __syncthreads();
    // ---- M3: S += K^T @ U ; refresh bf16 copy
    #pragma unroll
    for (int t = 0; t < 4; ++t) {
      int e = t * 16 + lr;
      f32x4 acc = {0.f, 0.f, 0.f, 0.f};
      short8 u0 = *(const short8*)(UT + SWZ(e, lk * 8));
      short8 u1 = *(const short8*)(UT + SWZ(e, 32 + lk * 8));
      acc = mfma16(a_kt0, u0, acc);
      acc = mfma16(a_kt1, u1, acc);
      float* sp = &STs[SWZ(e, r0)];
      f32x4 sv = *(const f32x4*)sp;
      sv += acc;
      *(f32x4*)sp = sv;
      u16x4 sb = {f2b(sv[0]), f2b(sv[1]), f2b(sv[2]), f2b(sv[3])};
      *(u16x4*)(SbT + SWZ(e, r0)) = sb;
    }
    __syncthreads();
  }
}

// ---------------------------------------------------------------------------
// Final GEMM + residual: out[b][c][l] = x[b][c][l] + sum_k o[b][l][k]*Wo[k][c]
// o is bf16 [b][l][c]; out fp32. grid (L/128, C/64, B), 256 thr.
__global__ __launch_bounds__(256) void k_final(
    const ushort_t* __restrict__ o, const float* __restrict__ Wo,
    const float* __restrict__ x, float* __restrict__ outp) {
  __shared__ float As[32 * 132];  // As[kk][row], stride 132 (conflict pad)
  __shared__ float Bs[32 * 64];
  int tid = threadIdx.x;
  int b = blockIdx.z;
  int n0 = blockIdx.y * 64;
  int l0 = blockIdx.x * 128;
  int ti = tid >> 4, tj = tid & 15;
  float acc[8][4];
  #pragma unroll
  for (int r = 0; r < 8; ++r)
    #pragma unroll
    for (int s = 0; s < 4; ++s) acc[r][s] = 0.f;
  const ushort_t* obase = o + ((size_t)b * L_ + l0) * C_;
  const float* wb = Wo + n0;
  for (int kb = 0; kb < C_; kb += 32) {
    #pragma unroll
    for (int it = 0; it < 4; ++it) {
      int e = tid + it * 256;          // row = e>>3 (0..127), c4 = e&7
      int row = e >> 3, c4 = e & 7;
      u16x4 lv = *(const u16x4*)(obase + (size_t)row * C_ + kb + c4 * 4);
      #pragma unroll
      for (int q = 0; q < 4; ++q) As[(c4 * 4 + q) * 132 + row] = b2f(lv[q]);
    }
    #pragma unroll
    for (int it = 0; it < 2; ++it) {
      int e = tid + it * 256;
      int kk = e >> 4, nq = e & 15;
      *(f32x4*)&Bs[kk * 64 + nq * 4] =
          *(const f32x4*)(wb + (size_t)(kb + kk) * C_ + nq * 4);
    }
    __syncthreads();
    #pragma unroll 8
    for (int kk = 0; kk < 32; ++kk) {
      f32x4 a0 = *(const f32x4*)&As[kk * 132 + ti * 8];
      f32x4 a1 = *(const f32x4*)&As[kk * 132 + ti * 8 + 4];
      f32x4 bv = *(const f32x4*)&Bs[kk * 64 + tj * 4];
      #pragma unroll
      for (int r = 0; r < 4; ++r)
        #pragma unroll
        for (int s = 0; s < 4; ++s) {
          acc[r][s]     += a0[r] * bv[s];
          acc[r + 4][s] += a1[r] * bv[s];
        }
    }
    __syncthreads();
  }
  #pragma unroll
  for (int s = 0; s < 4; ++s) {
    int n = n0 + tj * 4 + s;
    size_t base = ((size_t)b * C_ + n) * L_ + l0 + ti * 8;
    f32x4 xlo = *(const f32x4*)(x + base);
    f32x4 xhi = *(const f32x4*)(x + base + 4);
    f32x4 lo = {acc[0][s] + xlo[0], acc[1][s] + xlo[1],
                acc[2][s] + xlo[2], acc[3][s] + xlo[3]};
    f32x4 hi = {acc[4][s] + xhi[0], acc[5][s] + xhi[1],
                acc[6][s] + xhi[2], acc[7][s] + xhi[3]};
    *(f32x4*)(outp + base) = lo;
    *(f32x4*)(outp + base + 4) = hi;
  }
}

// ---------------------------------------------------------------------------
extern "C" void kernel_launch(void* const* d_in, const int* in_sizes, int n_in,
                              void* d_out, int out_size, void* d_ws, size_t ws_size,
                              hipStream_t stream) {
  (void)in_sizes; (void)n_in; (void)out_size; (void)ws_size;
  const float* x  = (const float*)d_in[0];
  const float* Wq = (const float*)d_in[1];
  const float* Wk = (const float*)d_in[2];
  const float* Wv = (const float*)d_in[3];
  const float* Wb = (const float*)d_in[4];
  const float* Wo = (const float*)d_in[5];
  float* outp = (float*)d_out;

  const size_t NE = (size_t)B_ * NH_ * L_ * D_;   // 25,165,824 elements
  ushort_t* q    = (ushort_t*)d_ws;               // bf16, 50.3 MB
  ushort_t* kbuf = q + NE;                        // bf16, 50.3 MB (-> K^T)
  ushort_t* v    = kbuf + NE;                     // bf16, 50.3 MB (-> Vw)
  float*    beta = (float*)(v + NE);              // fp32,  1.6 MB
  ushort_t* o    = (ushort_t*)(beta + (size_t)B_ * NH_ * L_);  // bf16, 50.3 MB
  ushort_t* kw   = o + NE;                        // bf16, 50.3 MB (new)
  ushort_t* aqk  = kw + NE;                       // bf16, 50.3 MB (new)
  // total ws use ~303.6 MB (< round-1's known-good 308 MB)

  k_beta<<<dim3(L_ / 256, B_), 256, 0, stream>>>(x, Wb, beta);
  k_proj<<<dim3(L_ / 128, NH_, B_), 256, 0, stream>>>(x, Wq, q, 1);
  k_proj<<<dim3(L_ / 128, NH_, B_), 256, 0, stream>>>(x, Wk, kbuf, 1);
  k_proj<<<dim3(L_ / 128, NH_, B_), 256, 0, stream>>>(x, Wv, v, 0);
  k_pre<<<dim3(NC_, BH_), 256, 0, stream>>>(q, kbuf, v, beta, kw, aqk);
  k_seq<<<dim3(BH_), 256, 0, stream>>>(q, kbuf, kw, v, aqk, o);
  k_final<<<dim3(L_ / 128, C_ / 64, B_), 256, 0, stream>>>(o, Wo, x, outp);
}

// Round 2
// 2082.369 us; speedup vs baseline: 1.3880x; 1.3880x over previous
//
#include <hip/hip_runtime.h>

// ---------------------------------------------------------------------------
// UNet DeltaNet forward, MI355X/gfx950 — round 5.
// fp32 in/out; intermediates bf16 (fp32 accumulation). All four big GEMMs
// (q/k/v projections, output projection) now run on MFMA 16x16x32 bf16 with
// hi/lo-split operands (error ~2^-17, i.e. fp32-equivalent) for the
// projections; Wo is single-bf16 (adds ~0.003 abs).
// Shapes: B=8, C=768, L=4096, n_heads=12, D=64, CHUNK=64, BH=96.
//
//  1) k_wprep x4 : W -> W^T bf16 hi + lo        (tiny)
//  2) k_xtr      : x[b][c][l] -> xt[b][l][c] bf16 hi+lo (hi=aqk buf, lo=kw buf)
//  3) k_beta     : beta = sigmoid(x^T @ Wb)     (fp32 VALU, small)
//  4) k_projm x3 : q/k = l2norm(silu(t@W)), v = silu(t@Wv) — MFMA, 3-term
//                  hi/lo product, no LDS, frags direct from global.
//  5) k_pre2     : per (chunk,bh): As=strict(b*KK^T) via MFMA; Aqk=tril(QK^T)
//                  via MFMA; K^T in place; 2-stage register-resident solve
//                  (I+As)X=[bK|bV] -> Kw, Vw.   52 KB LDS, 3 blk/CU.
//  6) k_seq      : serial 64-chunk scan per bh (unchanged, MFMA).
//  7) k_finalm   : out = x + o @ Wo — MFMA, A=Wo^T rows, B=o rows.
// Workspace: 6 x 50.33 MB + beta 1.57 MB + Wt 4.72 MB = 308.3 MB.
// ---------------------------------------------------------------------------

#define B_  8
#define C_  768
#define L_  4096
#define NH_ 12
#define D_  64
#define NC_ 64
#define BH_ 96

typedef unsigned short ushort_t;
typedef float f32x4 __attribute__((ext_vector_type(4)));
typedef unsigned short u16x4 __attribute__((ext_vector_type(4)));
typedef unsigned short u16x8 __attribute__((ext_vector_type(8)));
using short8 = __attribute__((ext_vector_type(8))) short;

__device__ __forceinline__ float b2f(ushort_t u) {
  union { unsigned u; float f; } x; x.u = ((unsigned)u) << 16; return x.f;
}
__device__ __forceinline__ ushort_t f2b(float f) {
  union { float f; unsigned u; } x; x.f = f;
  unsigned r = (x.u + 0x7FFFu + ((x.u >> 16) & 1u)) >> 16;
  return (ushort_t)r;
}
__device__ __forceinline__ f32x4 mfma16(short8 a, short8 b, f32x4 c) {
  return __builtin_amdgcn_mfma_f32_16x16x32_bf16(a, b, c, 0, 0, 0);
}

// XOR-swizzled [e][i] index for 64x64 bf16 tiles in k_seq.
#define SWZ(e, i) (((e) * 64) + ((i) ^ (((e) & 7) << 3)))

// ---------------------------------------------------------------------------
// W[cin][nout] fp32 -> Wt hi/lo bf16 [nout][cin]. grid (12,12), 256 thr.
__global__ __launch_bounds__(256) void k_wprep(
    const float* __restrict__ W, ushort_t* __restrict__ hi,
    ushort_t* __restrict__ lo) {
  __shared__ float ts[64 * 65];
  int tid = threadIdx.x;
  int c0 = blockIdx.x * 64;   // input-dim tile
  int n0 = blockIdx.y * 64;   // output-dim tile
  #pragma unroll
  for (int it = 0; it < 4; ++it) {
    int e = tid + it * 256;
    int r = e >> 4, c4 = (e & 15) * 4;
    *(f32x4*)&ts[r * 65 + c4] =
        *(const f32x4*)(W + (size_t)(c0 + r) * C_ + n0 + c4);
  }
  __syncthreads();
  #pragma unroll
  for (int it = 0; it < 4; ++it) {
    int e = tid + it * 256;
    int n = e >> 4, r4 = (e & 15) * 4;
    u16x4 hv, lv;
    #pragma unroll
    for (int q = 0; q < 4; ++q) {
      float w = ts[(r4 + q) * 65 + n];
      ushort_t h = f2b(w);
      hv[q] = h;
      lv[q] = f2b(w - b2f(h));
    }
    *(u16x4*)(hi + (size_t)(n0 + n) * C_ + c0 + r4) = hv;
    *(u16x4*)(lo + (size_t)(n0 + n) * C_ + c0 + r4) = lv;
  }
}

// ---------------------------------------------------------------------------
// x[b][c][l] fp32 -> xt hi/lo bf16 [b][l][c]. grid (64,12,8), 256 thr.
__global__ __launch_bounds__(256) void k_xtr(
    const float* __restrict__ x, ushort_t* __restrict__ hi,
    ushort_t* __restrict__ lo) {
  __shared__ float ts[64 * 65];
  int tid = threadIdx.x;
  int l0 = blockIdx.x * 64;
  int c0 = blockIdx.y * 64;
  int b = blockIdx.z;
  const float* xb = x + (size_t)b * C_ * L_;
  #pragma unroll
  for (int it = 0; it < 4; ++it) {
    int e = tid + it * 256;
    int ci = e >> 4, l4 = (e & 15) * 4;
    *(f32x4*)&ts[ci * 65 + l4] =
        *(const f32x4*)(xb + (size_t)(c0 + ci) * L_ + l0 + l4);
  }
  __syncthreads();
  #pragma unroll
  for (int it = 0; it < 4; ++it) {
    int e = tid + it * 256;
    int li = e >> 4, c4 = (e & 15) * 4;
    u16x4 hv, lv;
    #pragma unroll
    for (int q = 0; q < 4; ++q) {
      float w = ts[(c4 + q) * 65 + li];
      ushort_t h = f2b(w);
      hv[q] = h;
      lv[q] = f2b(w - b2f(h));
    }
    size_t base = ((size_t)b * L_ + l0 + li) * C_ + c0 + c4;
    *(u16x4*)(hi + base) = hv;
    *(u16x4*)(lo + base) = lv;
  }
}

// ---------------------------------------------------------------------------
// beta = sigmoid(x^T @ Wb); grid (L/256, B), 256 thr.
__global__ __launch_bounds__(256) void k_beta(
    const float* __restrict__ x, const float* __restrict__ Wb,
    float* __restrict__ beta) {
  __shared__ float wb[C_ * NH_];   // 36 KB
  int tid = threadIdx.x;
  for (int i = tid; i < C_ * NH_; i += 256) wb[i] = Wb[i];
  __syncthreads();
  int b = blockIdx.y;
  int l = blockIdx.x * 256 + tid;
  f32x4 a0 = {0.f, 0.f, 0.f, 0.f}, a1 = a0, a2 = a0;
  const float* xb = x + (size_t)b * C_ * L_ + l;
  for (int c = 0; c < C_; ++c) {
    float xv = xb[(size_t)c * L_];
    const f32x4* wr = (const f32x4*)&wb[c * NH_];
    a0 += xv * wr[0]; a1 += xv * wr[1]; a2 += xv * wr[2];
  }
  float* bp = beta + (size_t)b * NH_ * L_ + l;
  #pragma unroll
  for (int h = 0; h < 4; ++h) {
    bp[(size_t)h * L_]       = 1.f / (1.f + expf(-a0[h]));
    bp[(size_t)(h + 4) * L_] = 1.f / (1.f + expf(-a1[h]));
    bp[(size_t)(h + 8) * L_] = 1.f / (1.f + expf(-a2[h]));
  }
}

// ---------------------------------------------------------------------------
// MFMA projection: out[b][h][l][d] = epi( t[l][:] @ W[:][h*64+d] ).
// A = xt rows (hi/lo), B = Wt rows (hi/lo); 3-term product ~ fp32-exact.
// Block: 128 l x 64 d, 4 waves stacked in l. grid (L/128, NH, B), 256 thr.
__global__ __launch_bounds__(256) void k_projm(
    const ushort_t* __restrict__ xhi, const ushort_t* __restrict__ xlo,
    const ushort_t* __restrict__ whi, const ushort_t* __restrict__ wlo,
    ushort_t* __restrict__ outp, int norm) {
  int tid = threadIdx.x;
  int b = blockIdx.z, h = blockIdx.y;
  int l0 = blockIdx.x * 128;
  int wid = tid >> 6, lane = tid & 63;
  int lr = lane & 15, lk = lane >> 4;
  const ushort_t* xh = xhi + ((size_t)b * L_ + l0 + wid * 32 + lr) * C_ + lk * 8;
  const ushort_t* xl = xlo + ((size_t)b * L_ + l0 + wid * 32 + lr) * C_ + lk * 8;
  const ushort_t* wh = whi + ((size_t)h * 64 + lr) * C_ + lk * 8;
  const ushort_t* wl = wlo + ((size_t)h * 64 + lr) * C_ + lk * 8;
  f32x4 acc[2][4];
  #pragma unroll
  for (int mf = 0; mf < 2; ++mf)
    #pragma unroll
    for (int nf = 0; nf < 4; ++nf) acc[mf][nf] = (f32x4){0.f, 0.f, 0.f, 0.f};
  for (int kb = 0; kb < C_; kb += 32) {
    short8 ah[2], al[2], bh[4], bl[4];
    #pragma unroll
    for (int mf = 0; mf < 2; ++mf) {
      ah[mf] = *(const short8*)(xh + (size_t)mf * 16 * C_ + kb);
      al[mf] = *(const short8*)(xl + (size_t)mf * 16 * C_ + kb);
    }
    #pragma unroll
    for (int nf = 0; nf < 4; ++nf) {
      bh[nf] = *(const short8*)(wh + (size_t)nf * 16 * C_ + kb);
      bl[nf] = *(const short8*)(wl + (size_t)nf * 16 * C_ + kb);
    }
    #pragma unroll
    for (int mf = 0; mf < 2; ++mf)
      #pragma unroll
      for (int nf = 0; nf < 4; ++nf) {
        acc[mf][nf] = mfma16(ah[mf], bh[nf], acc[mf][nf]);
        acc[mf][nf] = mfma16(al[mf], bh[nf], acc[mf][nf]);
        acc[mf][nf] = mfma16(ah[mf], bl[nf], acc[mf][nf]);
      }
  }
  // epilogue: silu (+ optional l2norm over the 64-wide d at fixed row)
  #pragma unroll
  for (int mf = 0; mf < 2; ++mf)
    #pragma unroll
    for (int nf = 0; nf < 4; ++nf)
      #pragma unroll
      for (int r = 0; r < 4; ++r) {
        float xv = acc[mf][nf][r];
        acc[mf][nf][r] = xv / (1.f + expf(-xv));
      }
  if (norm) {
    #pragma unroll
    for (int mf = 0; mf < 2; ++mf)
      #pragma unroll
      for (int r = 0; r < 4; ++r) {
        float ss = 0.f;
        #pragma unroll
        for (int nf = 0; nf < 4; ++nf) ss += acc[mf][nf][r] * acc[mf][nf][r];
        ss += __shfl_xor(ss, 1); ss += __shfl_xor(ss, 2);
        ss += __shfl_xor(ss, 4); ss += __shfl_xor(ss, 8);
        float rs = rsqrtf(ss + 1e-6f);
        #pragma unroll
        for (int nf = 0; nf < 4; ++nf) acc[mf][nf][r] *= rs;
      }
  }
  // C-frag: row = lk*4 + r (within 16-block), col d = nf*16 + lr
  ushort_t* ob = outp +
      (((size_t)b * NH_ + h) * L_ + l0 + wid * 32 + lk * 4) * 64 + lr;
  #pragma unroll
  for (int mf = 0; mf < 2; ++mf)
    #pragma unroll
    for (int r = 0; r < 4; ++r)
      #pragma unroll
      for (int nf = 0; nf < 4; ++nf)
        ob[(size_t)(mf * 16 + r) * 64 + nf * 16] = f2b(acc[mf][nf][r]);
}

// ---------------------------------------------------------------------------
// k_pre2: per (chunk, bh): As = strict(b*KK^T) & Aqk = tril(QK^T) via MFMA;
// K^T in place; 2-stage register solve (I+As)X=[bK|bV] -> Kw, Vw.
// grid (NC, BH), 256 thr, 52 KB LDS (3 blk/CU).
__global__ __launch_bounds__(256) void k_pre2(
    const ushort_t* __restrict__ qg, ushort_t* kg, ushort_t* vg,
    const float* __restrict__ betag, ushort_t* __restrict__ kwg,
    ushort_t* __restrict__ aqg) {
  __shared__ float As[64 * 68];   // 17 KB  strict b*KK^T (0 on/above diag)
  __shared__ float XK[64 * 68];   // 17 KB  rhs/solution, K side
  __shared__ float XV[64 * 68];   // 17 KB  rhs/solution, V side
  int tid = threadIdx.x;
  int nc = blockIdx.x, bh = blockIdx.y;
  const size_t cb = ((size_t)bh * 64 + nc) * 4096;
  const float* bb = betag + (size_t)bh * L_ + nc * 64;
  int wid = tid >> 6, lane = tid & 63;
  int lr = lane & 15, lk = lane >> 4;
  // ---- phase A: fragments direct from global; MFMA KK^T and QK^T
  short8 kbf[4][2], ka[2], qa[2];
  #pragma unroll
  for (int nf = 0; nf < 4; ++nf)
    #pragma unroll
    for (int ks = 0; ks < 2; ++ks)
      kbf[nf][ks] = *(const short8*)(kg + cb +
          (size_t)(nf * 16 + lr) * 64 + ks * 32 + lk * 8);
  #pragma unroll
  for (int ks = 0; ks < 2; ++ks) {
    ka[ks] = *(const short8*)(kg + cb + (size_t)(wid * 16 + lr) * 64 + ks * 32 + lk * 8);
    qa[ks] = *(const short8*)(qg + cb + (size_t)(wid * 16 + lr) * 64 + ks * 32 + lk * 8);
  }
  f32x4 kk[4], qk[4];
  #pragma unroll
  for (int nf = 0; nf < 4; ++nf) {
    kk[nf] = (f32x4){0.f, 0.f, 0.f, 0.f};
    qk[nf] = (f32x4){0.f, 0.f, 0.f, 0.f};
    kk[nf] = mfma16(ka[0], kbf[nf][0], kk[nf]);
    kk[nf] = mfma16(ka[1], kbf[nf][1], kk[nf]);
    qk[nf] = mfma16(qa[0], kbf[nf][0], qk[nf]);
    qk[nf] = mfma16(qa[1], kbf[nf][1], qk[nf]);
  }
  float bi[4];
  #pragma unroll
  for (int r = 0; r < 4; ++r) bi[r] = bb[wid * 16 + lk * 4 + r];
  #pragma unroll
  for (int r = 0; r < 4; ++r) {
    int i = wid * 16 + lk * 4 + r;
    #pragma unroll
    for (int nf = 0; nf < 4; ++nf) {
      int j = nf * 16 + lr;
      As[i * 68 + j] = (j < i) ? bi[r] * kk[nf][r] : 0.f;
      aqg[cb + (size_t)i * 64 + j] = (j <= i) ? f2b(qk[nf][r]) : (ushort_t)0;
    }
  }
  // ---- stage XK = b*K, XV = b*V (fp32, stride 68)
  #pragma unroll
  for (int it = 0; it < 2; ++it) {
    int e = tid + it * 256;
    int i = e >> 3, c0 = (e & 7) * 8;
    float bv = bb[i];
    u16x8 kv8 = *(const u16x8*)(kg + cb + (size_t)i * 64 + c0);
    u16x8 vv8 = *(const u16x8*)(vg + cb + (size_t)i * 64 + c0);
    f32x4 klo = {bv*b2f(kv8[0]), bv*b2f(kv8[1]), bv*b2f(kv8[2]), bv*b2f(kv8[3])};
    f32x4 khi = {bv*b2f(kv8[4]), bv*b2f(kv8[5]), bv*b2f(kv8[6]), bv*b2f(kv8[7])};
    f32x4 vlo = {bv*b2f(vv8[0]), bv*b2f(vv8[1]), bv*b2f(vv8[2]), bv*b2f(vv8[3])};
    f32x4 vhi = {bv*b2f(vv8[4]), bv*b2f(vv8[5]), bv*b2f(vv8[6]), bv*b2f(vv8[7])};
    *(f32x4*)&XK[i * 68 + c0]     = klo;
    *(f32x4*)&XK[i * 68 + c0 + 4] = khi;
    *(f32x4*)&XV[i * 68 + c0]     = vlo;
    *(f32x4*)&XV[i * 68 + c0 + 4] = vhi;
  }
  __syncthreads();
  // ---- stage 1: waves 0-1 solve rows 0..31 (reg-resident columns);
  //              waves 2-3 scatter K^T to global from kbf.
  if (tid < 128) {
    float* Xc = (tid < 64) ? (XK + tid) : (XV + (tid - 64));
    float xr[32];
    #pragma unroll
    for (int i = 0; i < 32; ++i) xr[i] = Xc[i * 68];
    #pragma unroll
    for (int i = 1; i < 32; ++i) {
      float xi = xr[i];
      #pragma unroll
      for (int jb = 0; jb <= (i >> 2); ++jb) {   // As zero at/above diag
        f32x4 a4 = *(const f32x4*)&As[i * 68 + jb * 4];
        xi -= a4[0]*xr[jb*4] + a4[1]*xr[jb*4+1] + a4[2]*xr[jb*4+2] + a4[3]*xr[jb*4+3];
      }
      xr[i] = xi;
    }
    #pragma unroll
    for (int i = 1; i < 32; ++i) Xc[i * 68] = xr[i];
  } else {
    int ks = wid - 2;
    #pragma unroll
    for (int nf = 0; nf < 4; ++nf)
      #pragma unroll
      for (int jj = 0; jj < 8; ++jj) {
        int d = ks * 32 + lk * 8 + jj;
        kg[cb + (size_t)d * 64 + nf * 16 + lr] = (ushort_t)kbf[nf][ks][jj];
      }
  }
  __syncthreads();
  // ---- stage 2: waves 2-3 solve rows 32..63; waves 0-1 write top Kw/Vw.
  if (tid >= 128) {
    int col = tid - 128;
    float* Xc = (col < 64) ? (XK + col) : (XV + (col - 64));
    float xr[32];
    #pragma unroll
    for (int i = 0; i < 32; ++i) xr[i] = Xc[(32 + i) * 68];
    // apply the solved top 32 rows
    #pragma unroll
    for (int jb = 0; jb < 8; ++jb) {
      float xt0 = Xc[(jb*4+0)*68], xt1 = Xc[(jb*4+1)*68];
      float xt2 = Xc[(jb*4+2)*68], xt3 = Xc[(jb*4+3)*68];
      #pragma unroll
      for (int i = 0; i < 32; ++i) {
        f32x4 a4 = *(const f32x4*)&As[(32 + i) * 68 + jb * 4];
        xr[i] -= a4[0]*xt0 + a4[1]*xt1 + a4[2]*xt2 + a4[3]*xt3;
      }
    }
    // diagonal 32x32 block
    #pragma unroll
    for (int i = 1; i < 32; ++i) {
      float xi = xr[i];
      #pragma unroll
      for (int jb = 8; jb <= ((32 + i) >> 2); ++jb) {
        f32x4 a4 = *(const f32x4*)&As[(32 + i) * 68 + jb * 4];
        xi -= a4[0]*xr[jb*4-32] + a4[1]*xr[jb*4-31]
            + a4[2]*xr[jb*4-30] + a4[3]*xr[jb*4-29];
      }
      xr[i] = xi;
    }
    #pragma unroll
    for (int i = 0; i < 32; ++i) Xc[(32 + i) * 68] = xr[i];
  } else {
    #pragma unroll
    for (int it = 0; it < 4; ++it) {
      int u = tid + it * 128;               // 0..511: rows 0..31
      int i = u >> 4, d0 = (u & 15) * 4;
      f32x4 v4 = *(const f32x4*)&XK[i * 68 + d0];
      u16x4 pk = {f2b(v4[0]), f2b(v4[1]), f2b(v4[2]), f2b(v4[3])};
      *(u16x4*)(kwg + cb + (size_t)i * 64 + d0) = pk;
      f32x4 w4 = *(const f32x4*)&XV[i * 68 + d0];
      u16x4 pv = {f2b(w4[0]), f2b(w4[1]), f2b(w4[2]), f2b(w4[3])};
      *(u16x4*)(vg + cb + (size_t)i * 64 + d0) = pv;
    }
  }
  __syncthreads();
  // ---- all threads: write rows 32..63 of Kw/Vw
  #pragma unroll
  for (int it = 0; it < 2; ++it) {
    int u = tid + it * 256;                 // 0..511
    int i = 32 + (u >> 4), d0 = (u & 15) * 4;
    f32x4 v4 = *(const f32x4*)&XK[i * 68 + d0];
    u16x4 pk = {f2b(v4[0]), f2b(v4[1]), f2b(v4[2]), f2b(v4[3])};
    *(u16x4*)(kwg + cb + (size_t)i * 64 + d0) = pk;
    f32x4 w4 = *(const f32x4*)&XV[i * 68 + d0];
    u16x4 pv = {f2b(w4[0]), f2b(w4[1]), f2b(w4[2]), f2b(w4[3])};
    *(u16x4*)(vg + cb + (size_t)i * 64 + d0) = pv;
  }
}

// ---------------------------------------------------------------------------
// k_seq: serial 64-chunk scan per (b,h), MFMA 16x16x32 bf16.
// U = Vw - Kw*S ; O = Q*S + Aqk*U ; S += K^T*U.  grid (BH), 256 thr.
__global__ __launch_bounds__(256) void k_seq(
    const ushort_t* __restrict__ qg,  const ushort_t* __restrict__ ktg,
    const ushort_t* __restrict__ kwg, const ushort_t* __restrict__ vwg,
    const ushort_t* __restrict__ aqg, ushort_t* __restrict__ og) {
  __shared__ float    STs[64 * 64];   // 16 KB  S^T fp32 [e][d] (swizzled)
  __shared__ ushort_t SbT[64 * 64];   //  8 KB  S^T bf16
  __shared__ ushort_t UT [64 * 64];   //  8 KB  U^T bf16 [e][i]
  int tid = threadIdx.x, bh = blockIdx.x;
  int w  = tid >> 6, l = tid & 63;
  int lr = l & 15, lk = l >> 4;
  int mrow = w * 16 + lr;             // A-frag row (i for M1/M2, d for M3)
  int r0   = w * 16 + lk * 4;         // C/D-frag row base
  for (int i = tid; i < 4096; i += 256) { STs[i] = 0.f; SbT[i] = 0; }
  int b = bh / NH_, h = bh % NH_;
  ushort_t* ob = og + (size_t)b * L_ * C_ + h * 64;
  __syncthreads();
  for (int nc = 0; nc < NC_; ++nc) {
    const size_t cb = ((size_t)bh * 64 + nc) * 4096;
    const ushort_t* Kw = kwg + cb;
    const ushort_t* Qc = qg  + cb;
    const ushort_t* Aq = aqg + cb;
    const ushort_t* KT = ktg + cb;
    const ushort_t* Vw = vwg + cb;
    // hoist all global loads for this chunk (one latency hit per chunk)
    short8 a_kw0 = *(const short8*)(Kw + mrow * 64 + lk * 8);
    short8 a_kw1 = *(const short8*)(Kw + mrow * 64 + 32 + lk * 8);
    short8 a_q0  = *(const short8*)(Qc + mrow * 64 + lk * 8);
    short8 a_q1  = *(const short8*)(Qc + mrow * 64 + 32 + lk * 8);
    short8 a_aq0 = *(const short8*)(Aq + mrow * 64 + lk * 8);
    short8 a_aq1 = *(const short8*)(Aq + mrow * 64 + 32 + lk * 8);
    short8 a_kt0 = *(const short8*)(KT + mrow * 64 + lk * 8);
    short8 a_kt1 = *(const short8*)(KT + mrow * 64 + 32 + lk * 8);
    float vwv[4][4];
    #pragma unroll
    for (int t = 0; t < 4; ++t)
      #pragma unroll
      for (int r = 0; r < 4; ++r)
        vwv[t][r] = b2f(Vw[(size_t)(r0 + r) * 64 + t * 16 + lr]);
    // ---- M1: U = Vw - Kw @ S
    #pragma unroll
    for (int t = 0; t < 4; ++t) {
      int e = t * 16 + lr;
      f32x4 acc = {0.f, 0.f, 0.f, 0.f};
      short8 b0 = *(const short8*)(SbT + SWZ(e, lk * 8));
      short8 b1 = *(const short8*)(SbT + SWZ(e, 32 + lk * 8));
      acc = mfma16(a_kw0, b0, acc);
      acc = mfma16(a_kw1, b1, acc);
      u16x4 uo;
      #pragma unroll
      for (int r = 0; r < 4; ++r) uo[r] = f2b(vwv[t][r] - acc[r]);
      *(u16x4*)(UT + SWZ(e, r0)) = uo;
    }
    __syncthreads();
    // ---- M2: O = Q @ S + Aqk @ U  -> global bf16
    #pragma unroll
    for (int t = 0; t < 4; ++t) {
      int e = t * 16 + lr;
      f32x4 acc = {0.f, 0.f, 0.f, 0.f};
      short8 s0 = *(const short8*)(SbT + SWZ(e, lk * 8));
      short8 s1 = *(const short8*)(SbT + SWZ(e, 32 + lk * 8));
      short8 u0 = *(const short8*)(UT  + SWZ(e, lk * 8));
      short8 u1 = *(const short8*)(UT  + SWZ(e, 32 + lk * 8));
      acc = mfma16(a_q0,  s0, acc);
      acc = mfma16(a_q1,  s1, acc);
      acc = mfma16(a_aq0, u0, acc);
      acc = mfma16(a_aq1, u1, acc);
      #pragma unroll
      for (int r = 0; r < 4; ++r)
        ob[(size_t)(nc * 64 + r0 + r) * C_ + e] = f2b(acc[r]);
    }
    __syncthreads();
    // ---- M3: S += K^T @ U ; refresh bf16 copy
    #pragma unroll
    for (int t = 0; t < 4; ++t) {
      int e = t * 16 + lr;
      f32x4 acc = {0.f, 0.f, 0.f, 0.f};
      short8 u0 = *(const short8*)(UT + SWZ(e, lk * 8));
      short8 u1 = *(const short8*)(UT + SWZ(e, 32 + lk * 8));
      acc = mfma16(a_kt0, u0, acc);
      acc = mfma16(a_kt1, u1, acc);
      float* sp = &STs[SWZ(e, r0)];
      f32x4 sv = *(const f32x4*)sp;
      sv += acc;
      *(f32x4*)sp = sv;
      u16x4 sb = {f2b(sv[0]), f2b(sv[1]), f2b(sv[2]), f2b(sv[3])};
      *(u16x4*)(SbT + SWZ(e, r0)) = sb;
    }
    __syncthreads();
  }
}

// ---------------------------------------------------------------------------
// Final MFMA GEMM + residual: out[b][c][l] = x[b][c][l] + (o @ Wo)[l][c].
// A = Wo^T rows (bf16 hi), B = o rows. C[m=cout][n=l].
// Block: 64 cout x 128 l, 4 waves stacked in cout. grid (L/128, C/64, B).
__global__ __launch_bounds__(256) void k_finalm(
    const ushort_t* __restrict__ o, const ushort_t* __restrict__ wot,
    const float* __restrict__ x, float* __restrict__ outp) {
  int tid = threadIdx.x;
  int b = blockIdx.z;
  int c0 = blockIdx.y * 64;
  int l0 = blockIdx.x * 128;
  int wid = tid >> 6, lane = tid & 63;
  int lr = lane & 15, lk = lane >> 4;
  const ushort_t* ar = wot + (size_t)(c0 + wid * 16 + lr) * C_ + lk * 8;
  const ushort_t* br = o + ((size_t)b * L_ + l0 + lr) * C_ + lk * 8;
  f32x4 acc[8];
  #pragma unroll
  for (int nf = 0; nf < 8; ++nf) acc[nf] = (f32x4){0.f, 0.f, 0.f, 0.f};
  for (int kb = 0; kb < C_; kb += 32) {
    short8 av = *(const short8*)(ar + kb);
    #pragma unroll
    for (int nf = 0; nf < 8; ++nf) {
      short8 bv = *(const short8*)(br + (size_t)nf * 16 * C_ + kb);
      acc[nf] = mfma16(av, bv, acc[nf]);
    }
  }
  // C-frag: cout = c0 + wid*16 + lk*4 + r ; l = l0 + nf*16 + lr
  #pragma unroll
  for (int nf = 0; nf < 8; ++nf)
    #pragma unroll
    for (int r = 0; r < 4; ++r) {
      int cc = c0 + wid * 16 + lk * 4 + r;
      size_t idx = ((size_t)b * C_ + cc) * L_ + l0 + nf * 16 + lr;
      outp[idx] = acc[nf][r] + x[idx];
    }
}

// ---------------------------------------------------------------------------
extern "C" void kernel_launch(void* const* d_in, const int* in_sizes, int n_in,
                              void* d_out, int out_size, void* d_ws, size_t ws_size,
                              hipStream_t stream) {
  (void)in_sizes; (void)n_in; (void)out_size; (void)ws_size;
  const float* x  = (const float*)d_in[0];
  const float* Wq = (const float*)d_in[1];
  const float* Wk = (const float*)d_in[2];
  const float* Wv = (const float*)d_in[3];
  const float* Wb = (const float*)d_in[4];
  const float* Wo = (const float*)d_in[5];
  float* outp = (float*)d_out;

  const size_t NE = (size_t)B_ * NH_ * L_ * D_;   // 25,165,824 elements
  const size_t WE = (size_t)C_ * C_;              //    589,824 elements
  ushort_t* q    = (ushort_t*)d_ws;               // bf16, 50.3 MB
  ushort_t* kbuf = q + NE;                        // bf16, 50.3 MB (-> K^T)
  ushort_t* v    = kbuf + NE;                     // bf16, 50.3 MB (-> Vw)
  float*    beta = (float*)(v + NE);              // fp32,  1.6 MB
  ushort_t* o    = (ushort_t*)(beta + (size_t)B_ * NH_ * L_);  // bf16, 50.3 MB
  ushort_t* kw   = o + NE;                        // bf16, 50.3 MB (xt_lo alias)
  ushort_t* aqk  = kw + NE;                       // bf16, 50.3 MB (xt_hi alias)
  ushort_t* wt   = aqk + NE;                      // 4 x 1.18 MB  W^T hi bf16
  // total ws use: 6*50.33 + 1.57 + 4.72 = 308.3 MB
  ushort_t* xt_hi = aqk;                          // dead before k_pre2 writes aqk
  ushort_t* xt_lo = kw;                           // dead before k_pre2 writes kw
  ushort_t* wt_q = wt, *wt_k = wt + WE, *wt_v = wt + 2 * WE, *wt_o = wt + 3 * WE;
  ushort_t* wl_q = o, *wl_k = o + WE, *wl_v = o + 2 * WE, *wl_o = o + 3 * WE;
  // W-lo scratch lives in the head of o (o unwritten until k_seq)

  k_wprep<<<dim3(12, 12), 256, 0, stream>>>(Wq, wt_q, wl_q);
  k_wprep<<<dim3(12, 12), 256, 0, stream>>>(Wk, wt_k, wl_k);
  k_wprep<<<dim3(12, 12), 256, 0, stream>>>(Wv, wt_v, wl_v);
  k_wprep<<<dim3(12, 12), 256, 0, stream>>>(Wo, wt_o, wl_o);
  k_xtr<<<dim3(L_ / 64, C_ / 64, B_), 256, 0, stream>>>(x, xt_hi, xt_lo);
  k_beta<<<dim3(L_ / 256, B_), 256, 0, stream>>>(x, Wb, beta);
  k_projm<<<dim3(L_ / 128, NH_, B_), 256, 0, stream>>>(xt_hi, xt_lo, wt_q, wl_q, q, 1);
  k_projm<<<dim3(L_ / 128, NH_, B_), 256, 0, stream>>>(xt_hi, xt_lo, wt_k, wl_k, kbuf, 1);
  k_projm<<<dim3(L_ / 128, NH_, B_), 256, 0, stream>>>(xt_hi, xt_lo, wt_v, wl_v, v, 0);
  k_pre2<<<dim3(NC_, BH_), 256, 0, stream>>>(q, kbuf, v, beta, kw, aqk);
  k_seq<<<dim3(BH_), 256, 0, stream>>>(q, kbuf, kw, v, aqk, o);
  k_finalm<<<dim3(L_ / 128, C_ / 64, B_), 256, 0, stream>>>(o, wt_o, x, outp);
}

// Round 3
// 1077.576 us; speedup vs baseline: 2.6823x; 1.9325x over previous
//
#include <hip/hip_runtime.h>

// ---------------------------------------------------------------------------
// UNet DeltaNet forward, MI355X/gfx950 — round 6.
// fp32 in/out; intermediates bf16 (fp32 accumulation).
// Round-6: the three latency-bound k_projm dispatches (3x417us, MfmaUtil 12%)
// are replaced by ONE fused LDS-staged MFMA GEMM k_qkv (M=32768, N=2304,
// K=768, 3-term hi/lo product), using global_load_lds width-16 staging with
// a 16B-unit XOR swizzle (source-side swizzle + read-side swizzle, linear
// LDS dest). k_finalm likewise becomes LDS-staged (k_final2).
// Shapes: B=8, C=768, L=4096, n_heads=12, D=64, CHUNK=64, BH=96.
//
//  1) k_wprep x4 : W -> W^T bf16 hi + lo        (tiny)
//  2) k_xtr      : x[b][c][l] -> xt[b][l][c] bf16 hi+lo (hi=aqk buf, lo=kw buf)
//  3) k_beta     : beta = sigmoid(x^T @ Wb)     (fp32 VALU, small)
//  4) k_qkv      : fused q/k/v projection GEMM (MFMA, LDS-staged, 3-term)
//  5) k_pre2     : chunk-parallel KK^T/QK^T/solve -> Kw, Vw, Aqk, K^T
//  6) k_seq      : serial 64-chunk scan per bh (MFMA)
//  7) k_final2   : out = x + o @ Wo (MFMA, LDS-staged, 1-term)
// Workspace: 6 x 50.33 MB + beta 1.57 MB + Wt 4.72 MB = 308.3 MB.
// ---------------------------------------------------------------------------

#define B_  8
#define C_  768
#define L_  4096
#define NH_ 12
#define D_  64
#define NC_ 64
#define BH_ 96

typedef unsigned short ushort_t;
typedef float f32x4 __attribute__((ext_vector_type(4)));
typedef unsigned short u16x4 __attribute__((ext_vector_type(4)));
typedef unsigned short u16x8 __attribute__((ext_vector_type(8)));
using short8 = __attribute__((ext_vector_type(8))) short;

__device__ __forceinline__ float b2f(ushort_t u) {
  union { unsigned u; float f; } x; x.u = ((unsigned)u) << 16; return x.f;
}
__device__ __forceinline__ ushort_t f2b(float f) {
  union { float f; unsigned u; } x; x.f = f;
  unsigned r = (x.u + 0x7FFFu + ((x.u >> 16) & 1u)) >> 16;
  return (ushort_t)r;
}
__device__ __forceinline__ f32x4 mfma16(short8 a, short8 b, f32x4 c) {
  return __builtin_amdgcn_mfma_f32_16x16x32_bf16(a, b, c, 0, 0, 0);
}
// async global->LDS, 16 B per lane; LDS dest is wave-uniform base + lane*16.
__device__ __forceinline__ void gload16(const ushort_t* g, ushort_t* l) {
  __builtin_amdgcn_global_load_lds(
      (const __attribute__((address_space(1))) void*)(g),
      (__attribute__((address_space(3))) void*)(l), 16, 0, 0);
}

// XOR-swizzled [e][i] index for 64x64 bf16 tiles in k_seq.
#define SWZ(e, i) (((e) * 64) + ((i) ^ (((e) & 7) << 3)))

// ---------------------------------------------------------------------------
// W[cin][nout] fp32 -> Wt hi/lo bf16 [nout][cin]. grid (12,12), 256 thr.
__global__ __launch_bounds__(256) void k_wprep(
    const float* __restrict__ W, ushort_t* __restrict__ hi,
    ushort_t* __restrict__ lo) {
  __shared__ float ts[64 * 65];
  int tid = threadIdx.x;
  int c0 = blockIdx.x * 64;   // input-dim tile
  int n0 = blockIdx.y * 64;   // output-dim tile
  #pragma unroll
  for (int it = 0; it < 4; ++it) {
    int e = tid + it * 256;
    int r = e >> 4, c4 = (e & 15) * 4;
    *(f32x4*)&ts[r * 65 + c4] =
        *(const f32x4*)(W + (size_t)(c0 + r) * C_ + n0 + c4);
  }
  __syncthreads();
  #pragma unroll
  for (int it = 0; it < 4; ++it) {
    int e = tid + it * 256;
    int n = e >> 4, r4 = (e & 15) * 4;
    u16x4 hv, lv;
    #pragma unroll
    for (int q = 0; q < 4; ++q) {
      float w = ts[(r4 + q) * 65 + n];
      ushort_t h = f2b(w);
      hv[q] = h;
      lv[q] = f2b(w - b2f(h));
    }
    *(u16x4*)(hi + (size_t)(n0 + n) * C_ + c0 + r4) = hv;
    *(u16x4*)(lo + (size_t)(n0 + n) * C_ + c0 + r4) = lv;
  }
}

// ---------------------------------------------------------------------------
// x[b][c][l] fp32 -> xt hi/lo bf16 [b][l][c]. grid (64,12,8), 256 thr.
__global__ __launch_bounds__(256) void k_xtr(
    const float* __restrict__ x, ushort_t* __restrict__ hi,
    ushort_t* __restrict__ lo) {
  __shared__ float ts[64 * 65];
  int tid = threadIdx.x;
  int l0 = blockIdx.x * 64;
  int c0 = blockIdx.y * 64;
  int b = blockIdx.z;
  const float* xb = x + (size_t)b * C_ * L_;
  #pragma unroll
  for (int it = 0; it < 4; ++it) {
    int e = tid + it * 256;
    int ci = e >> 4, l4 = (e & 15) * 4;
    *(f32x4*)&ts[ci * 65 + l4] =
        *(const f32x4*)(xb + (size_t)(c0 + ci) * L_ + l0 + l4);
  }
  __syncthreads();
  #pragma unroll
  for (int it = 0; it < 4; ++it) {
    int e = tid + it * 256;
    int li = e >> 4, c4 = (e & 15) * 4;
    u16x4 hv, lv;
    #pragma unroll
    for (int q = 0; q < 4; ++q) {
      float w = ts[(c4 + q) * 65 + li];
      ushort_t h = f2b(w);
      hv[q] = h;
      lv[q] = f2b(w - b2f(h));
    }
    size_t base = ((size_t)b * L_ + l0 + li) * C_ + c0 + c4;
    *(u16x4*)(hi + base) = hv;
    *(u16x4*)(lo + base) = lv;
  }
}

// ---------------------------------------------------------------------------
// beta = sigmoid(x^T @ Wb); grid (L/256, B), 256 thr.
__global__ __launch_bounds__(256) void k_beta(
    const float* __restrict__ x, const float* __restrict__ Wb,
    float* __restrict__ beta) {
  __shared__ float wb[C_ * NH_];   // 36 KB
  int tid = threadIdx.x;
  for (int i = tid; i < C_ * NH_; i += 256) wb[i] = Wb[i];
  __syncthreads();
  int b = blockIdx.y;
  int l = blockIdx.x * 256 + tid;
  f32x4 a0 = {0.f, 0.f, 0.f, 0.f}, a1 = a0, a2 = a0;
  const float* xb = x + (size_t)b * C_ * L_ + l;
  for (int c = 0; c < C_; ++c) {
    float xv = xb[(size_t)c * L_];
    const f32x4* wr = (const f32x4*)&wb[c * NH_];
    a0 += xv * wr[0]; a1 += xv * wr[1]; a2 += xv * wr[2];
  }
  float* bp = beta + (size_t)b * NH_ * L_ + l;
  #pragma unroll
  for (int h = 0; h < 4; ++h) {
    bp[(size_t)h * L_]       = 1.f / (1.f + expf(-a0[h]));
    bp[(size_t)(h + 4) * L_] = 1.f / (1.f + expf(-a1[h]));
    bp[(size_t)(h + 8) * L_] = 1.f / (1.f + expf(-a2[h]));
  }
}

// ---------------------------------------------------------------------------
// Fused QKV projection GEMM: C[row][n] = silu(+norm)( xt[row][:] @ Wt[n][:] )
// row in [0, B*L), n in [0, 2304) = [q | k | v] columns. 3-term hi/lo MFMA.
// Tile 128x128, BK=32, 4 waves (each 32 rows x 128 cols). LDS 32 KB, staged
// via global_load_lds w=16 with 16B-unit swizzle s^((row>>1)&3) (2-way free).
// grid (256, 18), 256 thr.
__global__ __launch_bounds__(256) void k_qkv(
    const ushort_t* __restrict__ xhi, const ushort_t* __restrict__ xlo,
    const ushort_t* __restrict__ whi, const ushort_t* __restrict__ wlo,
    ushort_t* __restrict__ qout, ushort_t* __restrict__ kout,
    ushort_t* __restrict__ vout) {
  __shared__ __align__(16) ushort_t Ah[128 * 32];  // 8 KB each
  __shared__ __align__(16) ushort_t Al[128 * 32];
  __shared__ __align__(16) ushort_t Bh[128 * 32];
  __shared__ __align__(16) ushort_t Bl[128 * 32];
  int tid = threadIdx.x;
  int row0 = blockIdx.x * 128;          // global token row (b*L + l)
  int n0   = blockIdx.y * 128;          // fused output column
  int wid = tid >> 6, lane = tid & 63;
  int lr = lane & 15, lk = lane >> 4;
  f32x4 acc[2][8];
  #pragma unroll
  for (int mf = 0; mf < 2; ++mf)
    #pragma unroll
    for (int nf = 0; nf < 8; ++nf) acc[mf][nf] = (f32x4){0.f, 0.f, 0.f, 0.f};
  const ushort_t* ga  = xhi + (size_t)row0 * C_;
  const ushort_t* gal = xlo + (size_t)row0 * C_;
  const ushort_t* gb  = whi + (size_t)n0 * C_;
  const ushort_t* gbl = wlo + (size_t)n0 * C_;
  // precomputed read offsets (16B units): u = r*4 + (lk ^ ((r>>1)&3))
  int ra0 = wid * 32 + lr, ra1 = wid * 32 + 16 + lr;
  int ua0 = ra0 * 4 + (lk ^ ((ra0 >> 1) & 3));
  int ua1 = ra1 * 4 + (lk ^ ((ra1 >> 1) & 3));
  for (int kb = 0; kb < C_; kb += 32) {
    if (kb) __syncthreads();
    #pragma unroll
    for (int c = 0; c < 2; ++c) {
      int u = tid + c * 256;            // LDS 16B unit index (linear dest)
      int r = u >> 2, sp = u & 3;
      int s = sp ^ ((r >> 1) & 3);      // inverse-swizzled global slot
      size_t goff = (size_t)r * C_ + kb + s * 8;
      gload16(ga  + goff, &Ah[u * 8]);
      gload16(gal + goff, &Al[u * 8]);
      gload16(gb  + goff, &Bh[u * 8]);
      gload16(gbl + goff, &Bl[u * 8]);
    }
    __syncthreads();                    // drains vmcnt(0) before use
    short8 ah0 = *(const short8*)&Ah[ua0 * 8];
    short8 al0 = *(const short8*)&Al[ua0 * 8];
    short8 ah1 = *(const short8*)&Ah[ua1 * 8];
    short8 al1 = *(const short8*)&Al[ua1 * 8];
    #pragma unroll
    for (int nf = 0; nf < 8; ++nf) {
      int rb = nf * 16 + lr;
      int ub = rb * 4 + (lk ^ ((rb >> 1) & 3));
      short8 bh = *(const short8*)&Bh[ub * 8];
      short8 bl = *(const short8*)&Bl[ub * 8];
      acc[0][nf] = mfma16(ah0, bh, acc[0][nf]);
      acc[0][nf] = mfma16(al0, bh, acc[0][nf]);
      acc[0][nf] = mfma16(ah0, bl, acc[0][nf]);
      acc[1][nf] = mfma16(ah1, bh, acc[1][nf]);
      acc[1][nf] = mfma16(al1, bh, acc[1][nf]);
      acc[1][nf] = mfma16(ah1, bl, acc[1][nf]);
    }
  }
  // ---- epilogue: silu everywhere; l2norm per 64-wide head for q,k
  #pragma unroll
  for (int mf = 0; mf < 2; ++mf)
    #pragma unroll
    for (int nf = 0; nf < 8; ++nf)
      #pragma unroll
      for (int rr = 0; rr < 4; ++rr) {
        float xv = acc[mf][nf][rr];
        acc[mf][nf][rr] = xv / (1.f + expf(-xv));
      }
  int proj = n0 / 768;                  // 0=q, 1=k, 2=v (128 | 768)
  if (proj < 2) {
    #pragma unroll
    for (int mf = 0; mf < 2; ++mf)
      #pragma unroll
      for (int rr = 0; rr < 4; ++rr)
        #pragma unroll
        for (int g = 0; g < 2; ++g) {   // two heads per 128-col tile
          float ss = 0.f;
          #pragma unroll
          for (int nf = 4 * g; nf < 4 * g + 4; ++nf)
            ss += acc[mf][nf][rr] * acc[mf][nf][rr];
          ss += __shfl_xor(ss, 1); ss += __shfl_xor(ss, 2);
          ss += __shfl_xor(ss, 4); ss += __shfl_xor(ss, 8);
          float rs = rsqrtf(ss + 1e-6f);
          #pragma unroll
          for (int nf = 4 * g; nf < 4 * g + 4; ++nf) acc[mf][nf][rr] *= rs;
        }
  }
  ushort_t* outp = (proj == 0) ? qout : ((proj == 1) ? kout : vout);
  int nc0 = n0 - proj * 768;
  #pragma unroll
  for (int mf = 0; mf < 2; ++mf) {
    int row = row0 + wid * 32 + mf * 16 + lk * 4;   // b*L + l (rr stays in b)
    int b = row >> 12, l = row & 4095;
    #pragma unroll
    for (int nf = 0; nf < 8; ++nf) {
      int ncol = nc0 + nf * 16 + lr;
      int h = ncol >> 6, d = ncol & 63;
      ushort_t* op = outp + (((size_t)b * NH_ + h) * L_ + l) * 64 + d;
      #pragma unroll
      for (int rr = 0; rr < 4; ++rr)
        op[(size_t)rr * 64] = f2b(acc[mf][nf][rr]);
    }
  }
}

// ---------------------------------------------------------------------------
// k_pre2: per (chunk, bh): As = strict(b*KK^T) & Aqk = tril(QK^T) via MFMA;
// K^T in place; 2-stage register solve (I+As)X=[bK|bV] -> Kw, Vw.
// grid (NC, BH), 256 thr, 52 KB LDS.
__global__ __launch_bounds__(256) void k_pre2(
    const ushort_t* __restrict__ qg, ushort_t* kg, ushort_t* vg,
    const float* __restrict__ betag, ushort_t* __restrict__ kwg,
    ushort_t* __restrict__ aqg) {
  __shared__ float As[64 * 68];   // 17 KB  strict b*KK^T (0 on/above diag)
  __shared__ float XK[64 * 68];   // 17 KB  rhs/solution, K side
  __shared__ float XV[64 * 68];   // 17 KB  rhs/solution, V side
  int tid = threadIdx.x;
  int nc = blockIdx.x, bh = blockIdx.y;
  const size_t cb = ((size_t)bh * 64 + nc) * 4096;
  const float* bb = betag + (size_t)bh * L_ + nc * 64;
  int wid = tid >> 6, lane = tid & 63;
  int lr = lane & 15, lk = lane >> 4;
  // ---- phase A: fragments direct from global; MFMA KK^T and QK^T
  short8 kbf[4][2], ka[2], qa[2];
  #pragma unroll
  for (int nf = 0; nf < 4; ++nf)
    #pragma unroll
    for (int ks = 0; ks < 2; ++ks)
      kbf[nf][ks] = *(const short8*)(kg + cb +
          (size_t)(nf * 16 + lr) * 64 + ks * 32 + lk * 8);
  #pragma unroll
  for (int ks = 0; ks < 2; ++ks) {
    ka[ks] = *(const short8*)(kg + cb + (size_t)(wid * 16 + lr) * 64 + ks * 32 + lk * 8);
    qa[ks] = *(const short8*)(qg + cb + (size_t)(wid * 16 + lr) * 64 + ks * 32 + lk * 8);
  }
  f32x4 kk[4], qk[4];
  #pragma unroll
  for (int nf = 0; nf < 4; ++nf) {
    kk[nf] = (f32x4){0.f, 0.f, 0.f, 0.f};
    qk[nf] = (f32x4){0.f, 0.f, 0.f, 0.f};
    kk[nf] = mfma16(ka[0], kbf[nf][0], kk[nf]);
    kk[nf] = mfma16(ka[1], kbf[nf][1], kk[nf]);
    qk[nf] = mfma16(qa[0], kbf[nf][0], qk[nf]);
    qk[nf] = mfma16(qa[1], kbf[nf][1], qk[nf]);
  }
  float bi[4];
  #pragma unroll
  for (int r = 0; r < 4; ++r) bi[r] = bb[wid * 16 + lk * 4 + r];
  #pragma unroll
  for (int r = 0; r < 4; ++r) {
    int i = wid * 16 + lk * 4 + r;
    #pragma unroll
    for (int nf = 0; nf < 4; ++nf) {
      int j = nf * 16 + lr;
      As[i * 68 + j] = (j < i) ? bi[r] * kk[nf][r] : 0.f;
      aqg[cb + (size_t)i * 64 + j] = (j <= i) ? f2b(qk[nf][r]) : (ushort_t)0;
    }
  }
  // ---- stage XK = b*K, XV = b*V (fp32, stride 68)
  #pragma unroll
  for (int it = 0; it < 2; ++it) {
    int e = tid + it * 256;
    int i = e >> 3, c0 = (e & 7) * 8;
    float bv = bb[i];
    u16x8 kv8 = *(const u16x8*)(kg + cb + (size_t)i * 64 + c0);
    u16x8 vv8 = *(const u16x8*)(vg + cb + (size_t)i * 64 + c0);
    f32x4 klo = {bv*b2f(kv8[0]), bv*b2f(kv8[1]), bv*b2f(kv8[2]), bv*b2f(kv8[3])};
    f32x4 khi = {bv*b2f(kv8[4]), bv*b2f(kv8[5]), bv*b2f(kv8[6]), bv*b2f(kv8[7])};
    f32x4 vlo = {bv*b2f(vv8[0]), bv*b2f(vv8[1]), bv*b2f(vv8[2]), bv*b2f(vv8[3])};
    f32x4 vhi = {bv*b2f(vv8[4]), bv*b2f(vv8[5]), bv*b2f(vv8[6]), bv*b2f(vv8[7])};
    *(f32x4*)&XK[i * 68 + c0]     = klo;
    *(f32x4*)&XK[i * 68 + c0 + 4] = khi;
    *(f32x4*)&XV[i * 68 + c0]     = vlo;
    *(f32x4*)&XV[i * 68 + c0 + 4] = vhi;
  }
  __syncthreads();
  // ---- stage 1: waves 0-1 solve rows 0..31 (reg-resident columns);
  //              waves 2-3 scatter K^T to global from kbf.
  if (tid < 128) {
    float* Xc = (tid < 64) ? (XK + tid) : (XV + (tid - 64));
    float xr[32];
    #pragma unroll
    for (int i = 0; i < 32; ++i) xr[i] = Xc[i * 68];
    #pragma unroll
    for (int i = 1; i < 32; ++i) {
      float xi = xr[i];
      #pragma unroll
      for (int jb = 0; jb <= (i >> 2); ++jb) {   // As zero at/above diag
        f32x4 a4 = *(const f32x4*)&As[i * 68 + jb * 4];
        xi -= a4[0]*xr[jb*4] + a4[1]*xr[jb*4+1] + a4[2]*xr[jb*4+2] + a4[3]*xr[jb*4+3];
      }
      xr[i] = xi;
    }
    #pragma unroll
    for (int i = 1; i < 32; ++i) Xc[i * 68] = xr[i];
  } else {
    int ks = wid - 2;
    #pragma unroll
    for (int nf = 0; nf < 4; ++nf)
      #pragma unroll
      for (int jj = 0; jj < 8; ++jj) {
        int d = ks * 32 + lk * 8 + jj;
        kg[cb + (size_t)d * 64 + nf * 16 + lr] = (ushort_t)kbf[nf][ks][jj];
      }
  }
  __syncthreads();
  // ---- stage 2: waves 2-3 solve rows 32..63; waves 0-1 write top Kw/Vw.
  if (tid >= 128) {
    int col = tid - 128;
    float* Xc = (col < 64) ? (XK + col) : (XV + (col - 64));
    float xr[32];
    #pragma unroll
    for (int i = 0; i < 32; ++i) xr[i] = Xc[(32 + i) * 68];
    // apply the solved top 32 rows
    #pragma unroll
    for (int jb = 0; jb < 8; ++jb) {
      float xt0 = Xc[(jb*4+0)*68], xt1 = Xc[(jb*4+1)*68];
      float xt2 = Xc[(jb*4+2)*68], xt3 = Xc[(jb*4+3)*68];
      #pragma unroll
      for (int i = 0; i < 32; ++i) {
        f32x4 a4 = *(const f32x4*)&As[(32 + i) * 68 + jb * 4];
        xr[i] -= a4[0]*xt0 + a4[1]*xt1 + a4[2]*xt2 + a4[3]*xt3;
      }
    }
    // diagonal 32x32 block
    #pragma unroll
    for (int i = 1; i < 32; ++i) {
      float xi = xr[i];
      #pragma unroll
      for (int jb = 8; jb <= ((32 + i) >> 2); ++jb) {
        f32x4 a4 = *(const f32x4*)&As[(32 + i) * 68 + jb * 4];
        xi -= a4[0]*xr[jb*4-32] + a4[1]*xr[jb*4-31]
            + a4[2]*xr[jb*4-30] + a4[3]*xr[jb*4-29];
      }
      xr[i] = xi;
    }
    #pragma unroll
    for (int i = 0; i < 32; ++i) Xc[(32 + i) * 68] = xr[i];
  } else {
    #pragma unroll
    for (int it = 0; it < 4; ++it) {
      int u = tid + it * 128;               // 0..511: rows 0..31
      int i = u >> 4, d0 = (u & 15) * 4;
      f32x4 v4 = *(const f32x4*)&XK[i * 68 + d0];
      u16x4 pk = {f2b(v4[0]), f2b(v4[1]), f2b(v4[2]), f2b(v4[3])};
      *(u16x4*)(kwg + cb + (size_t)i * 64 + d0) = pk;
      f32x4 w4 = *(const f32x4*)&XV[i * 68 + d0];
      u16x4 pv = {f2b(w4[0]), f2b(w4[1]), f2b(w4[2]), f2b(w4[3])};
      *(u16x4*)(vg + cb + (size_t)i * 64 + d0) = pv;
    }
  }
  __syncthreads();
  // ---- all threads: write rows 32..63 of Kw/Vw
  #pragma unroll
  for (int it = 0; it < 2; ++it) {
    int u = tid + it * 256;                 // 0..511
    int i = 32 + (u >> 4), d0 = (u & 15) * 4;
    f32x4 v4 = *(const f32x4*)&XK[i * 68 + d0];
    u16x4 pk = {f2b(v4[0]), f2b(v4[1]), f2b(v4[2]), f2b(v4[3])};
    *(u16x4*)(kwg + cb + (size_t)i * 64 + d0) = pk;
    f32x4 w4 = *(const f32x4*)&XV[i * 68 + d0];
    u16x4 pv = {f2b(w4[0]), f2b(w4[1]), f2b(w4[2]), f2b(w4[3])};
    *(u16x4*)(vg + cb + (size_t)i * 64 + d0) = pv;
  }
}

// ---------------------------------------------------------------------------
// k_seq: serial 64-chunk scan per (b,h), MFMA 16x16x32 bf16.
// U = Vw - Kw*S ; O = Q*S + Aqk*U ; S += K^T*U.  grid (BH), 256 thr.
__global__ __launch_bounds__(256) void k_seq(
    const ushort_t* __restrict__ qg,  const ushort_t* __restrict__ ktg,
    const ushort_t* __restrict__ kwg, const ushort_t* __restrict__ vwg,
    const ushort_t* __restrict__ aqg, ushort_t* __restrict__ og) {
  __shared__ float    STs[64 * 64];   // 16 KB  S^T fp32 [e][d] (swizzled)
  __shared__ ushort_t SbT[64 * 64];   //  8 KB  S^T bf16
  __shared__ ushort_t UT [64 * 64];   //  8 KB  U^T bf16 [e][i]
  int tid = threadIdx.x, bh = blockIdx.x;
  int w  = tid >> 6, l = tid & 63;
  int lr = l & 15, lk = l >> 4;
  int mrow = w * 16 + lr;             // A-frag row (i for M1/M2, d for M3)
  int r0   = w * 16 + lk * 4;         // C/D-frag row base
  for (int i = tid; i < 4096; i += 256) { STs[i] = 0.f; SbT[i] = 0; }
  int b = bh / NH_, h = bh % NH_;
  ushort_t* ob = og + (size_t)b * L_ * C_ + h * 64;
  __syncthreads();
  for (int nc = 0; nc < NC_; ++nc) {
    const size_t cb = ((size_t)bh * 64 + nc) * 4096;
    const ushort_t* Kw = kwg + cb;
    const ushort_t* Qc = qg  + cb;
    const ushort_t* Aq = aqg + cb;
    const ushort_t* KT = ktg + cb;
    const ushort_t* Vw = vwg + cb;
    // hoist all global loads for this chunk (one latency hit per chunk)
    short8 a_kw0 = *(const short8*)(Kw + mrow * 64 + lk * 8);
    short8 a_kw1 = *(const short8*)(Kw + mrow * 64 + 32 + lk * 8);
    short8 a_q0  = *(const short8*)(Qc + mrow * 64 + lk * 8);
    short8 a_q1  = *(const short8*)(Qc + mrow * 64 + 32 + lk * 8);
    short8 a_aq0 = *(const short8*)(Aq + mrow * 64 + lk * 8);
    short8 a_aq1 = *(const short8*)(Aq + mrow * 64 + 32 + lk * 8);
    short8 a_kt0 = *(const short8*)(KT + mrow * 64 + lk * 8);
    short8 a_kt1 = *(const short8*)(KT + mrow * 64 + 32 + lk * 8);
    float vwv[4][4];
    #pragma unroll
    for (int t = 0; t < 4; ++t)
      #pragma unroll
      for (int r = 0; r < 4; ++r)
        vwv[t][r] = b2f(Vw[(size_t)(r0 + r) * 64 + t * 16 + lr]);
    // ---- M1: U = Vw - Kw @ S
    #pragma unroll
    for (int t = 0; t < 4; ++t) {
      int e = t * 16 + lr;
      f32x4 acc = {0.f, 0.f, 0.f, 0.f};
      short8 b0 = *(const short8*)(SbT + SWZ(e, lk * 8));
      short8 b1 = *(const short8*)(SbT + SWZ(e, 32 + lk * 8));
      acc = mfma16(a_kw0, b0, acc);
      acc = mfma16(a_kw1, b1, acc);
      u16x4 uo;
      #pragma unroll
      for (int r = 0; r < 4; ++r) uo[r] = f2b(vwv[t][r] - acc[r]);
      *(u16x4*)(UT + SWZ(e, r0)) = uo;
    }
    __syncthreads();
    // ---- M2: O = Q @ S + Aqk @ U  -> global bf16
    #pragma unroll
    for (int t = 0; t < 4; ++t) {
      int e = t * 16 + lr;
      f32x4 acc = {0.f, 0.f, 0.f, 0.f};
      short8 s0 = *(const short8*)(SbT + SWZ(e, lk * 8));
      short8 s1 = *(const short8*)(SbT + SWZ(e, 32 + lk * 8));
      short8 u0 = *(const short8*)(UT  + SWZ(e, lk * 8));
      short8 u1 = *(const short8*)(UT  + SWZ(e, 32 + lk * 8));
      acc = mfma16(a_q0,  s0, acc);
      acc = mfma16(a_q1,  s1, acc);
      acc = mfma16(a_aq0, u0, acc);
      acc = mfma16(a_aq1, u1, acc);
      #pragma unroll
      for (int r = 0; r < 4; ++r)
        ob[(size_t)(nc * 64 + r0 + r) * C_ + e] = f2b(acc[r]);
    }
    __syncthreads();
    // ---- M3: S += K^T @ U ; refresh bf16 copy
    #pragma unroll
    for (int t = 0; t < 4; ++t) {
      int e = t * 16 + lr;
      f32x4 acc = {0.f, 0.f, 0.f, 0.f};
      short8 u0 = *(const short8*)(UT + SWZ(e, lk * 8));
      short8 u1 = *(const short8*)(UT + SWZ(e, 32 + lk * 8));
      acc = mfma16(a_kt0, u0, acc);
      acc = mfma16(a_kt1, u1, acc);
      float* sp = &STs[SWZ(e, r0)];
      f32x4 sv = *(const f32x4*)sp;
      sv += acc;
      *(f32x4*)sp = sv;
      u16x4 sb = {f2b(sv[0]), f2b(sv[1]), f2b(sv[2]), f2b(sv[3])};
      *(u16x4*)(SbT + SWZ(e, r0)) = sb;
    }
    __syncthreads();
  }
}

// ---------------------------------------------------------------------------
// Final GEMM + residual, LDS-staged MFMA: out[b][c][l] = x + (o @ Wo)[l][c].
// A = Wo^T rows [cout][768] (bf16 hi), B = o rows [l][768]. Tile 128x128,
// BK=32, 16 KB LDS. grid (L/128, C/128, B), 256 thr.
__global__ __launch_bounds__(256) void k_final2(
    const ushort_t* __restrict__ o, const ushort_t* __restrict__ wot,
    const float* __restrict__ x, float* __restrict__ outp) {
  __shared__ __align__(16) ushort_t Ats[128 * 32];  // 8 KB (Wo^T tile)
  __shared__ __align__(16) ushort_t Bts[128 * 32];  // 8 KB (o tile)
  int tid = threadIdx.x;
  int b = blockIdx.z;
  int c0 = blockIdx.y * 128;
  int l0 = blockIdx.x * 128;
  int wid = tid >> 6, lane = tid & 63;
  int lr = lane & 15, lk = lane >> 4;
  f32x4 acc[2][8];
  #pragma unroll
  for (int mf = 0; mf < 2; ++mf)
    #pragma unroll
    for (int nf = 0; nf < 8; ++nf) acc[mf][nf] = (f32x4){0.f, 0.f, 0.f, 0.f};
  const ushort_t* ga = wot + (size_t)c0 * C_;
  const ushort_t* gb = o + ((size_t)b * L_ + l0) * C_;
  int ra0 = wid * 32 + lr, ra1 = wid * 32 + 16 + lr;
  int ua0 = ra0 * 4 + (lk ^ ((ra0 >> 1) & 3));
  int ua1 = ra1 * 4 + (lk ^ ((ra1 >> 1) & 3));
  for (int kb = 0; kb < C_; kb += 32) {
    if (kb) __syncthreads();
    #pragma unroll
    for (int c = 0; c < 2; ++c) {
      int u = tid + c * 256;
      int r = u >> 2, sp = u & 3;
      int s = sp ^ ((r >> 1) & 3);
      size_t goff = (size_t)r * C_ + kb + s * 8;
      gload16(ga + goff, &Ats[u * 8]);
      gload16(gb + goff, &Bts[u * 8]);
    }
    __syncthreads();
    short8 a0 = *(const short8*)&Ats[ua0 * 8];
    short8 a1 = *(const short8*)&Ats[ua1 * 8];
    #pragma unroll
    for (int nf = 0; nf < 8; ++nf) {
      int rb = nf * 16 + lr;
      int ub = rb * 4 + (lk ^ ((rb >> 1) & 3));
      short8 bv = *(const short8*)&Bts[ub * 8];
      acc[0][nf] = mfma16(a0, bv, acc[0][nf]);
      acc[1][nf] = mfma16(a1, bv, acc[1][nf]);
    }
  }
  // C-frag: cout = c0 + wid*32 + mf*16 + lk*4 + rr ; l = l0 + nf*16 + lr
  #pragma unroll
  for (int mf = 0; mf < 2; ++mf) {
    int cc0 = c0 + wid * 32 + mf * 16 + lk * 4;
    #pragma unroll
    for (int nf = 0; nf < 8; ++nf) {
      int ll = l0 + nf * 16 + lr;
      #pragma unroll
      for (int rr = 0; rr < 4; ++rr) {
        size_t idx = ((size_t)b * C_ + cc0 + rr) * L_ + ll;
        outp[idx] = acc[mf][nf][rr] + x[idx];
      }
    }
  }
}

// ---------------------------------------------------------------------------
extern "C" void kernel_launch(void* const* d_in, const int* in_sizes, int n_in,
                              void* d_out, int out_size, void* d_ws, size_t ws_size,
                              hipStream_t stream) {
  (void)in_sizes; (void)n_in; (void)out_size; (void)ws_size;
  const float* x  = (const float*)d_in[0];
  const float* Wq = (const float*)d_in[1];
  const float* Wk = (const float*)d_in[2];
  const float* Wv = (const float*)d_in[3];
  const float* Wb = (const float*)d_in[4];
  const float* Wo = (const float*)d_in[5];
  float* outp = (float*)d_out;

  const size_t NE = (size_t)B_ * NH_ * L_ * D_;   // 25,165,824 elements
  const size_t WE = (size_t)C_ * C_;              //    589,824 elements
  ushort_t* q    = (ushort_t*)d_ws;               // bf16, 50.3 MB
  ushort_t* kbuf = q + NE;                        // bf16, 50.3 MB (-> K^T)
  ushort_t* v    = kbuf + NE;                     // bf16, 50.3 MB (-> Vw)
  float*    beta = (float*)(v + NE);              // fp32,  1.6 MB
  ushort_t* o    = (ushort_t*)(beta + (size_t)B_ * NH_ * L_);  // bf16, 50.3 MB
  ushort_t* kw   = o + NE;                        // bf16, 50.3 MB (xt_lo alias)
  ushort_t* aqk  = kw + NE;                       // bf16, 50.3 MB (xt_hi alias)
  ushort_t* wt   = aqk + NE;                      // 4 x 1.18 MB  W^T hi bf16
  // total ws use: 6*50.33 + 1.57 + 4.72 = 308.3 MB
  ushort_t* xt_hi = aqk;                          // dead before k_pre2 writes aqk
  ushort_t* xt_lo = kw;                           // dead before k_pre2 writes kw
  ushort_t* wt_q = wt, *wt_o = wt + 3 * WE;
  ushort_t* wl_q = o;                             // lo halves live in head of o
  // wt_q/wt_k/wt_v contiguous = fused [2304][768] hi; wl_q.. likewise lo.

  k_wprep<<<dim3(12, 12), 256, 0, stream>>>(Wq, wt_q, wl_q);
  k_wprep<<<dim3(12, 12), 256, 0, stream>>>(Wk, wt + WE, o + WE);
  k_wprep<<<dim3(12, 12), 256, 0, stream>>>(Wv, wt + 2 * WE, o + 2 * WE);
  k_wprep<<<dim3(12, 12), 256, 0, stream>>>(Wo, wt_o, o + 3 * WE);
  k_xtr<<<dim3(L_ / 64, C_ / 64, B_), 256, 0, stream>>>(x, xt_hi, xt_lo);
  k_beta<<<dim3(L_ / 256, B_), 256, 0, stream>>>(x, Wb, beta);
  k_qkv<<<dim3((B_ * L_) / 128, 18), 256, 0, stream>>>(
      xt_hi, xt_lo, wt_q, wl_q, q, kbuf, v);
  k_pre2<<<dim3(NC_, BH_), 256, 0, stream>>>(q, kbuf, v, beta, kw, aqk);
  k_seq<<<dim3(BH_), 256, 0, stream>>>(q, kbuf, kw, v, aqk, o);
  k_final2<<<dim3(L_ / 128, C_ / 128, B_), 256, 0, stream>>>(o, wt_o, x, outp);
}